// Round 7
// baseline (190.481 us; speedup 1.0000x reference)
//
#include <hip/hip_runtime.h>
#include <hip/hip_bf16.h>
#include <stdint.h>

typedef __bf16 bf16;
typedef __bf16 bf16x4 __attribute__((ext_vector_type(4)));
typedef __bf16 bf16x8 __attribute__((ext_vector_type(8)));
typedef float  f32x4  __attribute__((ext_vector_type(4)));

#define L_TOT 1024
#define B_TOT 64
#define C_TOT 1024            // ENC2 (= K)
#define D_TOT 512             // DEC
#define E_TOT 512
#define M_TOT (L_TOT * B_TOT) // 65536
#define W_LD  (C_TOT + D_TOT) // 1536

#define BM 128
#define BN 128                // per-block e-extent (4 gy quarters)
#define BK 32
#define NT 256
#define NKT (C_TOT / BK)      // 32

__device__ __forceinline__ void gload_lds16(const void* g, void* l) {
  __builtin_amdgcn_global_load_lds(
      (const __attribute__((address_space(1))) unsigned int*)(uintptr_t)g,
      (__attribute__((address_space(3))) unsigned int*)(uintptr_t)l,
      16, 0, 0);
}

__device__ __forceinline__ bf16x8 cvt8(f32x4 a, f32x4 b) {
  bf16x8 o;
  o[0]=(bf16)a[0]; o[1]=(bf16)a[1]; o[2]=(bf16)a[2]; o[3]=(bf16)a[3];
  o[4]=(bf16)b[0]; o[5]=(bf16)b[1]; o[6]=(bf16)b[2]; o[7]=(bf16)b[3];
  return o;
}

__device__ __forceinline__ float tanh_fast(float x) {
  float e = __expf(2.0f * x);
  return 1.0f - __fdividef(2.0f, e + 1.0f);
}

// ---- prep: Wa_e (fp32, row stride 1536) -> bf16 [512][1024] in ws ----
__global__ void convert_we_kernel(const float* __restrict__ Wattn,
                                  bf16* __restrict__ Wb) {
  const int e = blockIdx.x;
  const int t = threadIdx.x;
  const float4 v = ((const float4*)(Wattn + (size_t)e * W_LD))[t];
  bf16x4 o;
  o[0]=(bf16)v.x; o[1]=(bf16)v.y; o[2]=(bf16)v.z; o[3]=(bf16)v.w;
  ((bf16x4*)(Wb + (size_t)e * C_TOT))[t] = o;
}

// ---- prep: sb[b][e] = sum_d s[b,d] * Wa_s[e,d] ----
__global__ void sb_kernel(const float* __restrict__ s,
                          const float* __restrict__ Wattn,
                          float* __restrict__ sb) {
  const int e = blockIdx.x;
  const int b = threadIdx.x;
  const float4* sr = (const float4*)(s + (size_t)b * D_TOT);
  const float4* wr = (const float4*)(Wattn + (size_t)e * W_LD + C_TOT);
  float acc = 0.f;
#pragma unroll 4
  for (int i = 0; i < D_TOT / 4; ++i) {
    float4 a = sr[i], w = wr[i];
    acc += a.x * w.x; acc += a.y * w.y; acc += a.z * w.z; acc += a.w * w.w;
  }
  sb[(size_t)b * E_TOT + e] = acc;
}

// ---- main GEMM + fused tanh/dot epilogue ----
// BM=128 x BN=128, BK=32; 256 threads = 4 waves (2m x 2n), wave tile 64x64.
// LDS 32 KB total (A dbuf 2x8K + B dbuf 2x8K) -> 4 independent blocks/CU.
// Pair-row XOR layout for both A and B tiles: logical row r (64B of 32 bf16),
// pair p=r>>1 (128B), seg s=(r&1)*4+sub stored at s^(p&7).
// Per tile t: stageB(t+1) [dist-1, L2-warm], LOADA regs(t+2) [dist-2, HBM],
// vmcnt(6) -> WRITEA(t+1), phase, vmcnt(4)+lgkm(0) -> raw barrier.
__global__ __launch_bounds__(NT, 4)
void gemm_tanh_dot_kernel(const float* __restrict__ A,
                          const bf16*  __restrict__ Wb,
                          const float* __restrict__ sb,
                          const float* __restrict__ Wv,
                          float* __restrict__ logitsQ) {
  __shared__ __align__(16) char smem[32768];
  char* const As0 = smem;
  char* const As1 = smem + 8192;
  char* const Bs0 = smem + 16384;
  char* const Bs1 = smem + 24576;

  const int tid  = threadIdx.x;
  const int lane = tid & 63;
  const int wid  = tid >> 6;        // 0..3
  const int wm   = wid >> 1;        // 0..1 m-half
  const int wn   = wid & 1;         // 0..1 e-half
  const int fr   = lane & 15;
  const int fg   = lane >> 4;

  const int blk = blockIdx.x;
  const int gx  = blk >> 2;         // 512 m-tiles
  const int gy  = blk & 3;          // 4 e-quarters; siblings adjacent -> L3 share
  const int m0  = gx << 7;
  const int e0  = gy << 7;

  // A staging: thread -> row=tid>>1 (0..127), 16 floats at (tid&1)*16.
  const float* gA = A + (size_t)(m0 + (tid >> 1)) * C_TOT + ((tid & 1) << 4);
  const int ar  = tid >> 1;
  const int ap  = ar >> 1;
  const int as0 = ((ar & 1) << 2) | ((tid & 1) << 1);
  const int awo0 = ap * 128 + (((as0    ) ^ (ap & 7)) << 4);
  const int awo1 = ap * 128 + (((as0 + 1) ^ (ap & 7)) << 4);

  // B staging: linear LDS dest (tid*16; 2nd issue +4096), pre-swizzled src.
  const int b_s = (tid & 7) ^ ((tid >> 3) & 7);
  const int b_r = ((tid >> 3) << 1) + (b_s >> 2);
  const bf16* gB = Wb + (size_t)(e0 + b_r) * C_TOT + ((b_s & 3) << 3);
  const int bdst = tid << 4;

  // fragment read offsets (+ am/bn * 1024)
  const int fxo = ((((fr & 1) << 2) | fg) ^ ((fr >> 1) & 7)) << 4;
  const int aro = ((wm << 5) + (fr >> 1)) * 128 + fxo;
  const int bro = ((wn << 5) + (fr >> 1)) * 128 + fxo;

  f32x4 acc[4][4];
#pragma unroll
  for (int i = 0; i < 4; ++i)
#pragma unroll
    for (int j = 0; j < 4; ++j)
      acc[i][j] = (f32x4){0.f, 0.f, 0.f, 0.f};

  f32x4 av00, av01, av02, av03, av10, av11, av12, av13;

  auto stageB = [&](char* Bp, int t) {
    const bf16* sp = gB + (t << 5);
    gload_lds16(sp,                        Bp + bdst);
    gload_lds16(sp + (size_t)64 * C_TOT,   Bp + bdst + 4096);
  };

#define LOADA(p, t)                                                            \
  { const float* ap_ = gA + ((t) << 5);                                        \
    asm volatile("global_load_dwordx4 %0, %1, off"           : "=v"(av##p##0) : "v"(ap_) : "memory"); \
    asm volatile("global_load_dwordx4 %0, %1, off offset:16" : "=v"(av##p##1) : "v"(ap_) : "memory"); \
    asm volatile("global_load_dwordx4 %0, %1, off offset:32" : "=v"(av##p##2) : "v"(ap_) : "memory"); \
    asm volatile("global_load_dwordx4 %0, %1, off offset:48" : "=v"(av##p##3) : "v"(ap_) : "memory"); }

#define WRITEA(Ap, p)                                                          \
  { *(bf16x8*)((Ap) + awo0) = cvt8(av##p##0, av##p##1);                        \
    *(bf16x8*)((Ap) + awo1) = cvt8(av##p##2, av##p##3); }

  auto phase = [&](const char* Ap, const char* Bp) {
    bf16x8 af[4], bf[4];
#pragma unroll
    for (int am = 0; am < 4; ++am) af[am] = *(const bf16x8*)(Ap + aro + am * 1024);
#pragma unroll
    for (int bn = 0; bn < 4; ++bn) bf[bn] = *(const bf16x8*)(Bp + bro + bn * 1024);
    __builtin_amdgcn_s_setprio(1);
#pragma unroll
    for (int am = 0; am < 4; ++am)
#pragma unroll
      for (int bn = 0; bn < 4; ++bn)
        acc[am][bn] = __builtin_amdgcn_mfma_f32_16x16x32_bf16(
            af[am], bf[bn], acc[am][bn], 0, 0, 0);
    __builtin_amdgcn_s_setprio(0);
  };

  // ---- prologue: B0,A0 staged+written; A1 in flight; publish tile 0 ----
  stageB(Bs0, 0);
  LOADA(0, 0);
  asm volatile("s_waitcnt vmcnt(0)" ::: "memory");
  __builtin_amdgcn_sched_barrier(0);
  WRITEA(As0, 0);
  LOADA(1, 1);
  asm volatile("s_waitcnt lgkmcnt(0)" ::: "memory");
  __builtin_amdgcn_s_barrier();
  __builtin_amdgcn_sched_barrier(0);

  // steady ledger at top of tile t: outstanding = [A(t+1) x4]
#pragma unroll 1
  for (int kp = 0; kp < 15; ++kp) {
    const int t = kp << 1;
    // ---- tile t (even): read As0/Bs0 ----
    stageB(Bs1, t + 1);                                  // +2 -> 6
    LOADA(0, t + 2);                                     // +4 -> 10
    asm volatile("s_waitcnt vmcnt(6)" ::: "memory");     // drain A(t+1)
    __builtin_amdgcn_sched_barrier(0);
    WRITEA(As1, 1);
    phase(As0, Bs0);
    asm volatile("s_waitcnt vmcnt(4) lgkmcnt(0)" ::: "memory");  // drain B(t+1)
    __builtin_amdgcn_s_barrier();
    __builtin_amdgcn_sched_barrier(0);
    // ---- tile t+1 (odd): read As1/Bs1 ----
    stageB(Bs0, t + 2);
    LOADA(1, t + 3);
    asm volatile("s_waitcnt vmcnt(6)" ::: "memory");     // drain A(t+2)
    __builtin_amdgcn_sched_barrier(0);
    WRITEA(As0, 0);
    phase(As1, Bs1);
    asm volatile("s_waitcnt vmcnt(4) lgkmcnt(0)" ::: "memory");  // drain B(t+2)
    __builtin_amdgcn_s_barrier();
    __builtin_amdgcn_sched_barrier(0);
  }
  // ---- tile 30 (even): stage B31; A31 already in set1; no new A loads ----
  stageB(Bs1, 31);                                       // out: [A31x4, B31x2]
  asm volatile("s_waitcnt vmcnt(2)" ::: "memory");       // drain A31
  __builtin_amdgcn_sched_barrier(0);
  WRITEA(As1, 1);
  phase(As0, Bs0);
  asm volatile("s_waitcnt vmcnt(0) lgkmcnt(0)" ::: "memory");
  __builtin_amdgcn_s_barrier();
  __builtin_amdgcn_sched_barrier(0);
  // ---- tile 31 (odd) ----
  phase(As1, Bs1);

  // ---- fused epilogue: +sb, tanh, *Wv, reduce over this block's 128 e ----
  float wv[4];
#pragma unroll
  for (int bn = 0; bn < 4; ++bn)
    wv[bn] = Wv[e0 + (wn << 6) + (bn << 4) + fr];

  float* red = (float*)smem;   // 2x128 floats in As0 (tile 31 used As1/Bs1)
#pragma unroll
  for (int am = 0; am < 4; ++am) {
#pragma unroll
    for (int j = 0; j < 4; ++j) {
      const int mloc = (wm << 6) + (am << 4) + (fg << 2) + j;  // 0..127
      const int bi = mloc & 63;                                // m = l*64+b
      const float* sbr = sb + (size_t)bi * E_TOT + e0 + (wn << 6) + fr;
      float c = 0.f;
#pragma unroll
      for (int bn = 0; bn < 4; ++bn)
        c += tanh_fast(acc[am][bn][j] + sbr[bn << 4]) * wv[bn];
      c += __shfl_xor(c, 1, 64);
      c += __shfl_xor(c, 2, 64);
      c += __shfl_xor(c, 4, 64);
      c += __shfl_xor(c, 8, 64);
      if (fr == 0) red[(wn << 7) + mloc] = c;
    }
  }
  __syncthreads();
  if (tid < BM)
    logitsQ[((size_t)gy << 16) + m0 + tid] = red[tid] + red[128 + tid];
#undef LOADA
#undef WRITEA
}

// ---- softmax over l per b; logits[m] = sum of 4 quarters; out[b][l] ----
__global__ __launch_bounds__(256)
void softmax_kernel(const float* __restrict__ lQ, float* __restrict__ out) {
  const int b = blockIdx.x;
  const int t = threadIdx.x;
  const int lane = t & 63, w = t >> 6;
  __shared__ float sm[8];
  float x[4];
  float mx = -3.4e38f;
#pragma unroll
  for (int i = 0; i < 4; ++i) {
    const int m = (t + (i << 8)) * 64 + b;
    x[i] = (lQ[m] + lQ[(1 << 16) + m]) + (lQ[(2 << 16) + m] + lQ[(3 << 16) + m]);
    mx = fmaxf(mx, x[i]);
  }
#pragma unroll
  for (int off = 1; off < 64; off <<= 1)
    mx = fmaxf(mx, __shfl_xor(mx, off, 64));
  if (lane == 0) sm[w] = mx;
  __syncthreads();
  mx = fmaxf(fmaxf(sm[0], sm[1]), fmaxf(sm[2], sm[3]));
  float ex[4], ssum = 0.f;
#pragma unroll
  for (int i = 0; i < 4; ++i) { ex[i] = __expf(x[i] - mx); ssum += ex[i]; }
#pragma unroll
  for (int off = 1; off < 64; off <<= 1)
    ssum += __shfl_xor(ssum, off, 64);
  if (lane == 0) sm[4 + w] = ssum;
  __syncthreads();
  const float inv = 1.0f / (sm[4] + sm[5] + sm[6] + sm[7]);
#pragma unroll
  for (int i = 0; i < 4; ++i)
    out[(size_t)b * 1024 + t + (i << 8)] = ex[i] * inv;
}

extern "C" void kernel_launch(void* const* d_in, const int* in_sizes, int n_in,
                              void* d_out, int out_size, void* d_ws, size_t ws_size,
                              hipStream_t stream) {
  const float* enc = (const float*)d_in[0];  // (1024, 64, 1024) fp32
  const float* s   = (const float*)d_in[1];  // (1, 64, 512)     fp32
  const float* Wat = (const float*)d_in[2];  // (512, 1536)      fp32
  const float* Wv  = (const float*)d_in[3];  // (1, 512)         fp32
  float* out = (float*)d_out;                // (64, 1024)       fp32

  char* ws = (char*)d_ws;
  bf16*  Wb      = (bf16*)ws;                                 // 1 MB
  float* sb      = (float*)(ws + (1u << 20));                 // 128 KB
  float* logitsQ = (float*)(ws + (1u << 20) + (128u << 10));  // 1 MB (4 quarters)

  convert_we_kernel<<<E_TOT, 256, 0, stream>>>(Wat, Wb);
  sb_kernel<<<E_TOT, 64, 0, stream>>>(s, Wat, sb);
  gemm_tanh_dot_kernel<<<(M_TOT / BM) * 4, NT, 0, stream>>>(enc, Wb, sb, Wv, logitsQ);
  softmax_kernel<<<B_TOT, 256, 0, stream>>>(logitsQ, out);
}

// Round 9
// 160.781 us; speedup vs baseline: 1.1847x; 1.1847x over previous
//
#include <hip/hip_runtime.h>
#include <hip/hip_bf16.h>
#include <stdint.h>

typedef __bf16 bf16;
typedef __bf16 bf16x4 __attribute__((ext_vector_type(4)));
typedef __bf16 bf16x8 __attribute__((ext_vector_type(8)));
typedef float  f32x4  __attribute__((ext_vector_type(4)));

#define L_TOT 1024
#define B_TOT 64
#define C_TOT 1024            // ENC2 (= K)
#define D_TOT 512             // DEC
#define E_TOT 512
#define M_TOT (L_TOT * B_TOT) // 65536
#define W_LD  (C_TOT + D_TOT) // 1536

#define BM 128
#define BN 128                // per-block e-extent (4 gy quarters)
#define BK 32
#define NT 256
#define NKT (C_TOT / BK)      // 32

__device__ __forceinline__ void gload_lds16(const void* g, void* l) {
  __builtin_amdgcn_global_load_lds(
      (const __attribute__((address_space(1))) unsigned int*)(uintptr_t)g,
      (__attribute__((address_space(3))) unsigned int*)(uintptr_t)l,
      16, 0, 0);
}

__device__ __forceinline__ bf16x8 cvt8(f32x4 a, f32x4 b) {
  bf16x8 o;
  o[0]=(bf16)a[0]; o[1]=(bf16)a[1]; o[2]=(bf16)a[2]; o[3]=(bf16)a[3];
  o[4]=(bf16)b[0]; o[5]=(bf16)b[1]; o[6]=(bf16)b[2]; o[7]=(bf16)b[3];
  return o;
}

__device__ __forceinline__ float tanh_fast(float x) {
  float e = __expf(2.0f * x);
  return 1.0f - __fdividef(2.0f, e + 1.0f);
}

// ---- prep: Wa_e (fp32, row stride 1536) -> bf16 [512][1024] in ws ----
__global__ void convert_we_kernel(const float* __restrict__ Wattn,
                                  bf16* __restrict__ Wb) {
  const int e = blockIdx.x;
  const int t = threadIdx.x;
  const float4 v = ((const float4*)(Wattn + (size_t)e * W_LD))[t];
  bf16x4 o;
  o[0]=(bf16)v.x; o[1]=(bf16)v.y; o[2]=(bf16)v.z; o[3]=(bf16)v.w;
  ((bf16x4*)(Wb + (size_t)e * C_TOT))[t] = o;
}

// ---- prep: sb[b][e] = sum_d s[b,d] * Wa_s[e,d] ----
__global__ void sb_kernel(const float* __restrict__ s,
                          const float* __restrict__ Wattn,
                          float* __restrict__ sb) {
  const int e = blockIdx.x;
  const int b = threadIdx.x;
  const float4* sr = (const float4*)(s + (size_t)b * D_TOT);
  const float4* wr = (const float4*)(Wattn + (size_t)e * W_LD + C_TOT);
  float acc = 0.f;
#pragma unroll 4
  for (int i = 0; i < D_TOT / 4; ++i) {
    float4 a = sr[i], w = wr[i];
    acc += a.x * w.x; acc += a.y * w.y; acc += a.z * w.z; acc += a.w * w.w;
  }
  sb[(size_t)b * E_TOT + e] = acc;
}

// ---- main GEMM + fused tanh/dot epilogue ----
// R6 engine VERBATIM (passed, absmax 6.1e-5): BM=128 x BN=128, BK=32,
// 4 waves (2m x 2n), LDS 32 KB dbuf, 4 blk/CU, per-tile counted-vmcnt.
// ONLY change vs R6: same-XCD sibling swizzle — gy=(blk>>3)&3,
// gx=(blk&7)|((blk>>5)<<3) puts the 4 blocks sharing an A-panel at
// blk i,i+8,i+16,i+24 -> same XCD (blk%8), co-resident -> the 512KB A-panel
// dedups in that XCD's 4MB L2 instead of being fetched by 4 XCDs (R6's
// FETCH=539MB -> expect ~280MB).
__global__ __launch_bounds__(NT, 4)
void gemm_tanh_dot_kernel(const float* __restrict__ A,
                          const bf16*  __restrict__ Wb,
                          const float* __restrict__ sb,
                          const float* __restrict__ Wv,
                          float* __restrict__ logitsQ) {
  __shared__ __align__(16) char smem[32768];
  char* const As0 = smem;
  char* const As1 = smem + 8192;
  char* const Bs0 = smem + 16384;
  char* const Bs1 = smem + 24576;

  const int tid  = threadIdx.x;
  const int lane = tid & 63;
  const int wid  = tid >> 6;        // 0..3
  const int wm   = wid >> 1;        // 0..1 m-half
  const int wn   = wid & 1;         // 0..1 e-half
  const int fr   = lane & 15;
  const int fg   = lane >> 4;

  const int blk = blockIdx.x;
  const int gx  = (blk & 7) | ((blk >> 5) << 3);  // 512 m-tiles
  const int gy  = (blk >> 3) & 3;                 // siblings i,i+8,i+16,i+24 (same XCD)
  const int m0  = gx << 7;
  const int e0  = gy << 7;

  // A staging: thread -> row=tid>>1 (0..127), 16 floats at (tid&1)*16.
  const float* gA = A + (size_t)(m0 + (tid >> 1)) * C_TOT + ((tid & 1) << 4);
  const int ar  = tid >> 1;
  const int ap  = ar >> 1;
  const int as0 = ((ar & 1) << 2) | ((tid & 1) << 1);
  const int awo0 = ap * 128 + (((as0    ) ^ (ap & 7)) << 4);
  const int awo1 = ap * 128 + (((as0 + 1) ^ (ap & 7)) << 4);

  // B staging: linear LDS dest (tid*16; 2nd issue +4096), pre-swizzled src.
  const int b_s = (tid & 7) ^ ((tid >> 3) & 7);
  const int b_r = ((tid >> 3) << 1) + (b_s >> 2);
  const bf16* gB = Wb + (size_t)(e0 + b_r) * C_TOT + ((b_s & 3) << 3);
  const int bdst = tid << 4;

  // fragment read offsets (+ am/bn * 1024)
  const int fxo = ((((fr & 1) << 2) | fg) ^ ((fr >> 1) & 7)) << 4;
  const int aro = ((wm << 5) + (fr >> 1)) * 128 + fxo;
  const int bro = ((wn << 5) + (fr >> 1)) * 128 + fxo;

  f32x4 acc[4][4];
#pragma unroll
  for (int i = 0; i < 4; ++i)
#pragma unroll
    for (int j = 0; j < 4; ++j)
      acc[i][j] = (f32x4){0.f, 0.f, 0.f, 0.f};

  f32x4 av00, av01, av02, av03, av10, av11, av12, av13;

  auto stageB = [&](char* Bp, int t) {
    const bf16* sp = gB + (t << 5);
    gload_lds16(sp,                        Bp + bdst);
    gload_lds16(sp + (size_t)64 * C_TOT,   Bp + bdst + 4096);
  };

#define LOADA(p, t)                                                            \
  { const float* ap_ = gA + ((t) << 5);                                        \
    asm volatile("global_load_dwordx4 %0, %1, off"           : "=v"(av##p##0) : "v"(ap_) : "memory"); \
    asm volatile("global_load_dwordx4 %0, %1, off offset:16" : "=v"(av##p##1) : "v"(ap_) : "memory"); \
    asm volatile("global_load_dwordx4 %0, %1, off offset:32" : "=v"(av##p##2) : "v"(ap_) : "memory"); \
    asm volatile("global_load_dwordx4 %0, %1, off offset:48" : "=v"(av##p##3) : "v"(ap_) : "memory"); }

#define WRITEA(Ap, p)                                                          \
  { *(bf16x8*)((Ap) + awo0) = cvt8(av##p##0, av##p##1);                        \
    *(bf16x8*)((Ap) + awo1) = cvt8(av##p##2, av##p##3); }

  auto phase = [&](const char* Ap, const char* Bp) {
    bf16x8 af[4], bf[4];
#pragma unroll
    for (int am = 0; am < 4; ++am) af[am] = *(const bf16x8*)(Ap + aro + am * 1024);
#pragma unroll
    for (int bn = 0; bn < 4; ++bn) bf[bn] = *(const bf16x8*)(Bp + bro + bn * 1024);
    __builtin_amdgcn_s_setprio(1);
#pragma unroll
    for (int am = 0; am < 4; ++am)
#pragma unroll
      for (int bn = 0; bn < 4; ++bn)
        acc[am][bn] = __builtin_amdgcn_mfma_f32_16x16x32_bf16(
            af[am], bf[bn], acc[am][bn], 0, 0, 0);
    __builtin_amdgcn_s_setprio(0);
  };

  // ---- prologue: B0,A0 staged+written; A1 in flight; publish tile 0 ----
  stageB(Bs0, 0);
  LOADA(0, 0);
  asm volatile("s_waitcnt vmcnt(0)" ::: "memory");
  __builtin_amdgcn_sched_barrier(0);
  WRITEA(As0, 0);
  LOADA(1, 1);
  asm volatile("s_waitcnt lgkmcnt(0)" ::: "memory");
  __builtin_amdgcn_s_barrier();
  __builtin_amdgcn_sched_barrier(0);

  // steady ledger at top of tile t: outstanding = [A(t+1) x4]
#pragma unroll 1
  for (int kp = 0; kp < 15; ++kp) {
    const int t = kp << 1;
    // ---- tile t (even): read As0/Bs0 ----
    stageB(Bs1, t + 1);                                  // +2 -> 6
    LOADA(0, t + 2);                                     // +4 -> 10
    asm volatile("s_waitcnt vmcnt(6)" ::: "memory");     // drain A(t+1)
    __builtin_amdgcn_sched_barrier(0);
    WRITEA(As1, 1);
    phase(As0, Bs0);
    asm volatile("s_waitcnt vmcnt(4) lgkmcnt(0)" ::: "memory");  // drain B(t+1)
    __builtin_amdgcn_s_barrier();
    __builtin_amdgcn_sched_barrier(0);
    // ---- tile t+1 (odd): read As1/Bs1 ----
    stageB(Bs0, t + 2);
    LOADA(1, t + 3);
    asm volatile("s_waitcnt vmcnt(6)" ::: "memory");     // drain A(t+2)
    __builtin_amdgcn_sched_barrier(0);
    WRITEA(As0, 0);
    phase(As1, Bs1);
    asm volatile("s_waitcnt vmcnt(4) lgkmcnt(0)" ::: "memory");  // drain B(t+2)
    __builtin_amdgcn_s_barrier();
    __builtin_amdgcn_sched_barrier(0);
  }
  // ---- tile 30 (even): stage B31; A31 already in set1; no new A loads ----
  stageB(Bs1, 31);                                       // out: [A31x4, B31x2]
  asm volatile("s_waitcnt vmcnt(2)" ::: "memory");       // drain A31
  __builtin_amdgcn_sched_barrier(0);
  WRITEA(As1, 1);
  phase(As0, Bs0);
  asm volatile("s_waitcnt vmcnt(0) lgkmcnt(0)" ::: "memory");
  __builtin_amdgcn_s_barrier();
  __builtin_amdgcn_sched_barrier(0);
  // ---- tile 31 (odd) ----
  phase(As1, Bs1);

  // ---- fused epilogue: +sb, tanh, *Wv, reduce over this block's 128 e ----
  float wv[4];
#pragma unroll
  for (int bn = 0; bn < 4; ++bn)
    wv[bn] = Wv[e0 + (wn << 6) + (bn << 4) + fr];

  float* red = (float*)smem;   // 2x128 floats in As0 (tile 31 used As1/Bs1)
#pragma unroll
  for (int am = 0; am < 4; ++am) {
#pragma unroll
    for (int j = 0; j < 4; ++j) {
      const int mloc = (wm << 6) + (am << 4) + (fg << 2) + j;  // 0..127
      const int bi = mloc & 63;                                // m = l*64+b
      const float* sbr = sb + (size_t)bi * E_TOT + e0 + (wn << 6) + fr;
      float c = 0.f;
#pragma unroll
      for (int bn = 0; bn < 4; ++bn)
        c += tanh_fast(acc[am][bn][j] + sbr[bn << 4]) * wv[bn];
      c += __shfl_xor(c, 1, 64);
      c += __shfl_xor(c, 2, 64);
      c += __shfl_xor(c, 4, 64);
      c += __shfl_xor(c, 8, 64);
      if (fr == 0) red[(wn << 7) + mloc] = c;
    }
  }
  __syncthreads();
  if (tid < BM)
    logitsQ[((size_t)gy << 16) + m0 + tid] = red[tid] + red[128 + tid];
#undef LOADA
#undef WRITEA
}

// ---- softmax over l per b; logits[m] = sum of 4 quarters; out[b][l] ----
__global__ __launch_bounds__(256)
void softmax_kernel(const float* __restrict__ lQ, float* __restrict__ out) {
  const int b = blockIdx.x;
  const int t = threadIdx.x;
  const int lane = t & 63, w = t >> 6;
  __shared__ float sm[8];
  float x[4];
  float mx = -3.4e38f;
#pragma unroll
  for (int i = 0; i < 4; ++i) {
    const int m = (t + (i << 8)) * 64 + b;
    x[i] = (lQ[m] + lQ[(1 << 16) + m]) + (lQ[(2 << 16) + m] + lQ[(3 << 16) + m]);
    mx = fmaxf(mx, x[i]);
  }
#pragma unroll
  for (int off = 1; off < 64; off <<= 1)
    mx = fmaxf(mx, __shfl_xor(mx, off, 64));
  if (lane == 0) sm[w] = mx;
  __syncthreads();
  mx = fmaxf(fmaxf(sm[0], sm[1]), fmaxf(sm[2], sm[3]));
  float ex[4], ssum = 0.f;
#pragma unroll
  for (int i = 0; i < 4; ++i) { ex[i] = __expf(x[i] - mx); ssum += ex[i]; }
#pragma unroll
  for (int off = 1; off < 64; off <<= 1)
    ssum += __shfl_xor(ssum, off, 64);
  if (lane == 0) sm[4 + w] = ssum;
  __syncthreads();
  const float inv = 1.0f / (sm[4] + sm[5] + sm[6] + sm[7]);
#pragma unroll
  for (int i = 0; i < 4; ++i)
    out[(size_t)b * 1024 + t + (i << 8)] = ex[i] * inv;
}

extern "C" void kernel_launch(void* const* d_in, const int* in_sizes, int n_in,
                              void* d_out, int out_size, void* d_ws, size_t ws_size,
                              hipStream_t stream) {
  const float* enc = (const float*)d_in[0];  // (1024, 64, 1024) fp32
  const float* s   = (const float*)d_in[1];  // (1, 64, 512)     fp32
  const float* Wat = (const float*)d_in[2];  // (512, 1536)      fp32
  const float* Wv  = (const float*)d_in[3];  // (1, 512)         fp32
  float* out = (float*)d_out;                // (64, 1024)       fp32

  char* ws = (char*)d_ws;
  bf16*  Wb      = (bf16*)ws;                                 // 1 MB
  float* sb      = (float*)(ws + (1u << 20));                 // 128 KB
  float* logitsQ = (float*)(ws + (1u << 20) + (128u << 10));  // 1 MB (4 quarters)

  convert_we_kernel<<<E_TOT, 256, 0, stream>>>(Wat, Wb);
  sb_kernel<<<E_TOT, 64, 0, stream>>>(s, Wat, sb);
  gemm_tanh_dot_kernel<<<(M_TOT / BM) * 4, NT, 0, stream>>>(enc, Wb, sb, Wv, logitsQ);
  softmax_kernel<<<B_TOT, 256, 0, stream>>>(logitsQ, out);
}

// Round 10
// 155.122 us; speedup vs baseline: 1.2279x; 1.0365x over previous
//
#include <hip/hip_runtime.h>
#include <hip/hip_bf16.h>
#include <stdint.h>

typedef __bf16 bf16;
typedef __bf16 bf16x4 __attribute__((ext_vector_type(4)));
typedef __bf16 bf16x8 __attribute__((ext_vector_type(8)));
typedef float  f32x4  __attribute__((ext_vector_type(4)));

#define L_TOT 1024
#define B_TOT 64
#define C_TOT 1024            // ENC2 (= K)
#define D_TOT 512             // DEC
#define E_TOT 512
#define M_TOT (L_TOT * B_TOT) // 65536
#define W_LD  (C_TOT + D_TOT) // 1536

#define BM 256
#define BN 256                // per-block e-extent (2 gy halves)
#define BK 64
#define NT 512
#define NKT (C_TOT / BK)      // 16

__device__ __forceinline__ void gload_lds16(const void* g, void* l) {
  __builtin_amdgcn_global_load_lds(
      (const __attribute__((address_space(1))) unsigned int*)(uintptr_t)g,
      (__attribute__((address_space(3))) unsigned int*)(uintptr_t)l,
      16, 0, 0);
}

__device__ __forceinline__ bf16x8 cvt8(f32x4 a, f32x4 b) {
  bf16x8 o;
  o[0]=(bf16)a[0]; o[1]=(bf16)a[1]; o[2]=(bf16)a[2]; o[3]=(bf16)a[3];
  o[4]=(bf16)b[0]; o[5]=(bf16)b[1]; o[6]=(bf16)b[2]; o[7]=(bf16)b[3];
  return o;
}

__device__ __forceinline__ float tanh_fast(float x) {
  float e = __expf(2.0f * x);
  return 1.0f - __fdividef(2.0f, e + 1.0f);
}

// ---- prep: Wa_e (fp32, row stride 1536) -> bf16 [512][1024] in ws ----
__global__ void convert_we_kernel(const float* __restrict__ Wattn,
                                  bf16* __restrict__ Wb) {
  const int e = blockIdx.x;
  const int t = threadIdx.x;
  const float4 v = ((const float4*)(Wattn + (size_t)e * W_LD))[t];
  bf16x4 o;
  o[0]=(bf16)v.x; o[1]=(bf16)v.y; o[2]=(bf16)v.z; o[3]=(bf16)v.w;
  ((bf16x4*)(Wb + (size_t)e * C_TOT))[t] = o;
}

// ---- prep: sb[b][e] = sum_d s[b,d] * Wa_s[e,d] ----
__global__ void sb_kernel(const float* __restrict__ s,
                          const float* __restrict__ Wattn,
                          float* __restrict__ sb) {
  const int e = blockIdx.x;
  const int b = threadIdx.x;
  const float4* sr = (const float4*)(s + (size_t)b * D_TOT);
  const float4* wr = (const float4*)(Wattn + (size_t)e * W_LD + C_TOT);
  float acc = 0.f;
#pragma unroll 4
  for (int i = 0; i < D_TOT / 4; ++i) {
    float4 a = sr[i], w = wr[i];
    acc += a.x * w.x; acc += a.y * w.y; acc += a.z * w.z; acc += a.w * w.w;
  }
  sb[(size_t)b * E_TOT + e] = acc;
}

// ---- main GEMM + fused tanh/dot epilogue: m201-style 8-phase schedule ----
// BM=256 x BN=256, BK=64; 512 threads = 8 waves (2m x 4n), wave tile 128x64,
// acc[8][4].  LDS 128KB = dbuf x (A 32K bf16 + B 32K bf16), 1 blk/CU.
// Layout both tiles: [256 rows][64 k] bf16, seg j (16B) of row r at j^(r&7).
// Per K-tile: 4 phases {ds_read 8 frags | stage issues | barrier | lgkm(0) |
// setprio | 16 MFMA | setprio | barrier}.  vmcnt(4) at ph2 (drains A(t+1)
// regs), vmcnt(8) before ph3's closing barrier (drains B(t+1) DMA; leaves
// A(t+2)x8 in flight across the tile boundary).
__global__ __launch_bounds__(NT, 1)
void gemm_tanh_dot_kernel(const float* __restrict__ A,
                          const bf16*  __restrict__ Wb,
                          const float* __restrict__ sb,
                          const float* __restrict__ Wv,
                          float* __restrict__ logitsH) {
  __shared__ __align__(16) char smem[131072];
  char* const bufA0 = smem;
  char* const bufA1 = smem + 32768;
  char* const bufB0 = smem + 65536;
  char* const bufB1 = smem + 98304;

  const int tid  = threadIdx.x;
  const int lane = tid & 63;
  const int wid  = tid >> 6;        // 0..7
  const int wm   = wid >> 2;        // 0..1 m-half (128 rows each)
  const int wn   = wid & 3;         // 0..3 e-slice (64 each)
  const int fr   = lane & 15;
  const int fg   = lane >> 4;

  const int blk = blockIdx.x;       // 512
  const int gx  = (blk & 7) | ((blk >> 4) << 3);  // 256 m-tiles
  const int gy  = (blk >> 3) & 1;                 // halves; (i,i+8) same XCD
  const int m0  = gx << 8;
  const int e0  = gy << 8;

  // A staging: thread -> row r=tid>>1 (0..255), 32 floats at (tid&1)*32.
  const float* gA = A + (size_t)(m0 + (tid >> 1)) * C_TOT + ((tid & 1) << 5);
  const int ar = tid >> 1;
  int awof[4];
#pragma unroll
  for (int w = 0; w < 4; ++w)
    awof[w] = ar * 128 + (((((tid & 1) << 2) | w) ^ (ar & 7)) << 4);

  // B staging: linear dest tid*16 + i*8192; pre-swizzled global source.
  const bf16* gB = Wb + (size_t)(e0 + (tid >> 3)) * C_TOT
                 + (((tid & 7) ^ ((tid >> 3) & 7)) << 3);
  const int bdst = tid << 4;

  // fragment read bases: row*128 + ((kk*4+fg)^(fr&7))*16
  const int aro0 = ((wm << 7) + fr) * 128;
  const int bro0 = ((wn << 6) + fr) * 128;
  const int xseg0 = (((fg) ^ (fr & 7)) << 4);        // kk=0
  const int xseg1 = (((4 + fg) ^ (fr & 7)) << 4);    // kk=1

  f32x4 acc[8][4];
#pragma unroll
  for (int i = 0; i < 8; ++i)
#pragma unroll
    for (int j = 0; j < 4; ++j)
      acc[i][j] = (f32x4){0.f, 0.f, 0.f, 0.f};

  f32x4 av00,av01,av02,av03,av04,av05,av06,av07;
  f32x4 av10,av11,av12,av13,av14,av15,av16,av17;
  bf16x8 bfr0, bfr1, bfr2, bfr3;

#define LOADA_H(S, T, H)  /* half H of A(T) into set S (4 dwordx4) */         \
  { const float* ap_ = gA + ((T) << 6);                                        \
    if (H == 0) {                                                              \
      asm volatile("global_load_dwordx4 %0, %1, off"           : "=v"(av##S##0) : "v"(ap_) : "memory"); \
      asm volatile("global_load_dwordx4 %0, %1, off offset:16" : "=v"(av##S##1) : "v"(ap_) : "memory"); \
      asm volatile("global_load_dwordx4 %0, %1, off offset:32" : "=v"(av##S##2) : "v"(ap_) : "memory"); \
      asm volatile("global_load_dwordx4 %0, %1, off offset:48" : "=v"(av##S##3) : "v"(ap_) : "memory"); \
    } else {                                                                   \
      asm volatile("global_load_dwordx4 %0, %1, off offset:64" : "=v"(av##S##4) : "v"(ap_) : "memory"); \
      asm volatile("global_load_dwordx4 %0, %1, off offset:80" : "=v"(av##S##5) : "v"(ap_) : "memory"); \
      asm volatile("global_load_dwordx4 %0, %1, off offset:96" : "=v"(av##S##6) : "v"(ap_) : "memory"); \
      asm volatile("global_load_dwordx4 %0, %1, off offset:112": "=v"(av##S##7) : "v"(ap_) : "memory"); \
    } }

#define STAGEB2(BBUF, T, I0)                                                   \
  { const bf16* sp_ = gB + ((T) << 6);                                         \
    gload_lds16(sp_ + (I0)     * 65536, (BBUF) + bdst + (I0)     * 8192);      \
    gload_lds16(sp_ + ((I0)+1) * 65536, (BBUF) + bdst + ((I0)+1) * 8192); }

#define WRITEA2(S, ABUF, W0)                                                   \
  { *(bf16x8*)((ABUF) + awof[W0])   = cvt8(av##S##_P2(W0,0), av##S##_P2(W0,1));\
    *(bf16x8*)((ABUF) + awof[W0+1]) = cvt8(av##S##_P2(W0+2,0), av##S##_P2(W0+2,1)); }
// helper token paste: av set S regs 2w, 2w+1
#define av0_P2(W,O) av0##_J(W,O)
#define av1_P2(W,O) av1##_J(W,O)
#define av0_J(W,O) AV0_##W##_##O
#define av1_J(W,O) AV1_##W##_##O
// simpler: write explicit WRITEA halves below instead of generic macro.
#undef WRITEA2
#undef av0_P2
#undef av1_P2
#undef av0_J
#undef av1_J

#define WRITEA_LO(S, ABUF)                                                     \
  { *(bf16x8*)((ABUF) + awof[0]) = cvt8(av##S##0, av##S##1);                   \
    *(bf16x8*)((ABUF) + awof[1]) = cvt8(av##S##2, av##S##3); }
#define WRITEA_HI(S, ABUF)                                                     \
  { *(bf16x8*)((ABUF) + awof[2]) = cvt8(av##S##4, av##S##5);                   \
    *(bf16x8*)((ABUF) + awof[3]) = cvt8(av##S##6, av##S##7); }

#define MFMA16(H)                                                              \
  __builtin_amdgcn_sched_barrier(0);                                           \
  __builtin_amdgcn_s_setprio(1);                                               \
  _Pragma("unroll")                                                            \
  for (int i_ = 0; i_ < 4; ++i_) {                                             \
    acc[(H)*4+i_][0] = __builtin_amdgcn_mfma_f32_16x16x32_bf16(af_[i_], bfr0, acc[(H)*4+i_][0], 0,0,0); \
    acc[(H)*4+i_][1] = __builtin_amdgcn_mfma_f32_16x16x32_bf16(af_[i_], bfr1, acc[(H)*4+i_][1], 0,0,0); \
    acc[(H)*4+i_][2] = __builtin_amdgcn_mfma_f32_16x16x32_bf16(af_[i_], bfr2, acc[(H)*4+i_][2], 0,0,0); \
    acc[(H)*4+i_][3] = __builtin_amdgcn_mfma_f32_16x16x32_bf16(af_[i_], bfr3, acc[(H)*4+i_][3], 0,0,0); \
  }                                                                            \
  __builtin_amdgcn_s_setprio(0);                                               \
  __builtin_amdgcn_sched_barrier(0);

#define RD_A(ACUR, XS, H)                                                      \
  bf16x8 af_[4];                                                               \
  _Pragma("unroll")                                                            \
  for (int i_ = 0; i_ < 4; ++i_)                                               \
    af_[i_] = *(const bf16x8*)((ACUR) + aro0 + ((H)*4+i_) * 2048 + (XS));
#define RD_B(BCUR, XS)                                                         \
  bfr0 = *(const bf16x8*)((BCUR) + bro0 + 0 * 2048 + (XS));                    \
  bfr1 = *(const bf16x8*)((BCUR) + bro0 + 1 * 2048 + (XS));                    \
  bfr2 = *(const bf16x8*)((BCUR) + bro0 + 2 * 2048 + (XS));                    \
  bfr3 = *(const bf16x8*)((BCUR) + bro0 + 3 * 2048 + (XS));

#define BAR() __builtin_amdgcn_s_barrier();
#define LGKM0() asm volatile("s_waitcnt lgkmcnt(0)" ::: "memory");

// One K-tile.  AC/BC = current bufs; AN/BN_ = next bufs; SW = av set written
// (A(t+1)); SL = av set loaded (A(t+2)); T = tile index.
// DO_B: stage B(t+1); DO_L: load A(t+2); ENDVM: trailing vmcnt immediate.
#define KTILE(AC, BC, AN, BN_, SW, SL, T, DO_B, DO_L, ENDVM)                   \
  { /* ph0: kk0 h0 */                                                          \
    { RD_A(AC, xseg0, 0) RD_B(BC, xseg0)                                       \
      if (DO_B) STAGEB2(BN_, (T)+1, 0);                                        \
      BAR(); LGKM0(); MFMA16(0) BAR(); }                                       \
    /* ph1: kk0 h1 */                                                          \
    { RD_A(AC, xseg0, 1)                                                       \
      if (DO_B) STAGEB2(BN_, (T)+1, 2);                                        \
      BAR(); LGKM0(); MFMA16(1) BAR(); }                                       \
    /* ph2: kk1 h0 */                                                          \
    { asm volatile("s_waitcnt vmcnt(4)" ::: "memory");                         \
      __builtin_amdgcn_sched_barrier(0);                                       \
      RD_A(AC, xseg1, 0) RD_B(BC, xseg1)                                       \
      WRITEA_LO(SW, AN);                                                       \
      if (DO_L) LOADA_H(SL, (T)+2, 0);                                         \
      BAR(); LGKM0(); MFMA16(0) BAR(); }                                       \
    /* ph3: kk1 h1 */                                                          \
    { RD_A(AC, xseg1, 1)                                                       \
      WRITEA_HI(SW, AN);                                                       \
      if (DO_L) LOADA_H(SL, (T)+2, 1);                                         \
      BAR(); LGKM0(); MFMA16(1)                                                \
      asm volatile("s_waitcnt vmcnt(" #ENDVM ")" ::: "memory");                \
      __builtin_amdgcn_sched_barrier(0);                                       \
      BAR(); } }

  // ---- prologue: B0 DMA + A0 regs; drain; write A0; load A1; publish ----
  { const bf16* sp_ = gB;
    gload_lds16(sp_,          bufB0 + bdst);
    gload_lds16(sp_ +  65536, bufB0 + bdst + 8192);
    gload_lds16(sp_ + 131072, bufB0 + bdst + 16384);
    gload_lds16(sp_ + 196608, bufB0 + bdst + 24576); }
  LOADA_H(0, 0, 0); LOADA_H(0, 0, 1);
  asm volatile("s_waitcnt vmcnt(0)" ::: "memory");
  __builtin_amdgcn_sched_barrier(0);
  WRITEA_LO(0, bufA0); WRITEA_HI(0, bufA0);
  LOADA_H(1, 1, 0); LOADA_H(1, 1, 1);
  LGKM0(); BAR();
  __builtin_amdgcn_sched_barrier(0);
  // entering tile 0: outstanding = [A1 x8]

  // tiles 0..13: even uses (A0c=bufA0,B0c=bufB0; write set1->bufA1, load set0)
#pragma unroll 1
  for (int kp = 0; kp < 7; ++kp) {
    const int t = kp << 1;
    KTILE(bufA0, bufB0, bufA1, bufB1, 1, 0, t,     1, (t     <= 13), 8)
    KTILE(bufA1, bufB1, bufA0, bufB0, 0, 1, t + 1, (t+1 <= 13), (t + 1 <= 13), 8)
  }
  // tile 14 (cur=0): stage B15, write A15 (set1), no A-loads, end drain 0
  KTILE(bufA0, bufB0, bufA1, bufB1, 1, 0, 14, 1, 0, 0)
  // tile 15 (cur=1): pure compute
  { { RD_A(bufA1, xseg0, 0) RD_B(bufB1, xseg0) BAR(); LGKM0(); MFMA16(0) BAR(); }
    { RD_A(bufA1, xseg0, 1)                    BAR(); LGKM0(); MFMA16(1) BAR(); }
    { RD_A(bufA1, xseg1, 0) RD_B(bufB1, xseg1) BAR(); LGKM0(); MFMA16(0) BAR(); }
    { RD_A(bufA1, xseg1, 1)                    BAR(); LGKM0(); MFMA16(1) BAR(); } }

  // ---- fused epilogue: +sb, tanh, *Wv, reduce over this block's 256 e ----
  float wv[4];
#pragma unroll
  for (int bn = 0; bn < 4; ++bn)
    wv[bn] = Wv[e0 + (wn << 6) + (bn << 4) + fr];

  float* red = (float*)smem;   // [4 wn][256 m] = 4KB in bufA0 region
#pragma unroll
  for (int am = 0; am < 8; ++am) {
#pragma unroll
    for (int j = 0; j < 4; ++j) {
      const int mloc = (wm << 7) + (am << 4) + (fg << 2) + j;  // 0..255
      const int bi = mloc & 63;                                // m = l*64+b
      const float* sbr = sb + (size_t)bi * E_TOT + e0 + (wn << 6) + fr;
      float c = 0.f;
#pragma unroll
      for (int bn = 0; bn < 4; ++bn)
        c += tanh_fast(acc[am][bn][j] + sbr[bn << 4]) * wv[bn];
      c += __shfl_xor(c, 1, 64);
      c += __shfl_xor(c, 2, 64);
      c += __shfl_xor(c, 4, 64);
      c += __shfl_xor(c, 8, 64);
      if (fr == 0) red[(wn << 8) + mloc] = c;
    }
  }
  __syncthreads();
  if (tid < BM) {
    float v = red[tid] + red[256 + tid] + red[512 + tid] + red[768 + tid];
    logitsH[((size_t)gy << 16) + m0 + tid] = v;
  }
#undef LOADA_H
#undef STAGEB2
#undef WRITEA_LO
#undef WRITEA_HI
#undef MFMA16
#undef RD_A
#undef RD_B
#undef BAR
#undef LGKM0
#undef KTILE
}

// ---- softmax over l per b; logits[m] = lH0[m]+lH1[m], m = l*64+b ----
__global__ __launch_bounds__(256)
void softmax_kernel(const float* __restrict__ lH, float* __restrict__ out) {
  const int b = blockIdx.x;
  const int t = threadIdx.x;
  const int lane = t & 63, w = t >> 6;
  __shared__ float sm[8];
  float x[4];
  float mx = -3.4e38f;
#pragma unroll
  for (int i = 0; i < 4; ++i) {
    const int m = (t + (i << 8)) * 64 + b;
    x[i] = lH[m] + lH[M_TOT + m];
    mx = fmaxf(mx, x[i]);
  }
#pragma unroll
  for (int off = 1; off < 64; off <<= 1)
    mx = fmaxf(mx, __shfl_xor(mx, off, 64));
  if (lane == 0) sm[w] = mx;
  __syncthreads();
  mx = fmaxf(fmaxf(sm[0], sm[1]), fmaxf(sm[2], sm[3]));
  float ex[4], ssum = 0.f;
#pragma unroll
  for (int i = 0; i < 4; ++i) { ex[i] = __expf(x[i] - mx); ssum += ex[i]; }
#pragma unroll
  for (int off = 1; off < 64; off <<= 1)
    ssum += __shfl_xor(ssum, off, 64);
  if (lane == 0) sm[4 + w] = ssum;
  __syncthreads();
  const float inv = 1.0f / (sm[4] + sm[5] + sm[6] + sm[7]);
#pragma unroll
  for (int i = 0; i < 4; ++i)
    out[(size_t)b * 1024 + t + (i << 8)] = ex[i] * inv;
}

extern "C" void kernel_launch(void* const* d_in, const int* in_sizes, int n_in,
                              void* d_out, int out_size, void* d_ws, size_t ws_size,
                              hipStream_t stream) {
  const float* enc = (const float*)d_in[0];  // (1024, 64, 1024) fp32
  const float* s   = (const float*)d_in[1];  // (1, 64, 512)     fp32
  const float* Wat = (const float*)d_in[2];  // (512, 1536)      fp32
  const float* Wv  = (const float*)d_in[3];  // (1, 512)         fp32
  float* out = (float*)d_out;                // (64, 1024)       fp32

  char* ws = (char*)d_ws;
  bf16*  Wb      = (bf16*)ws;                                 // 1 MB
  float* sb      = (float*)(ws + (1u << 20));                 // 128 KB
  float* logitsH = (float*)(ws + (1u << 20) + (128u << 10));  // 512 KB

  convert_we_kernel<<<E_TOT, 256, 0, stream>>>(Wat, Wb);
  sb_kernel<<<E_TOT, 64, 0, stream>>>(s, Wat, sb);
  gemm_tanh_dot_kernel<<<(M_TOT / BM) * 2, NT, 0, stream>>>(enc, Wb, sb, Wv, logitsH);
  softmax_kernel<<<B_TOT, 256, 0, stream>>>(logitsH, out);
}